// Round 1
// baseline (746.593 us; speedup 1.0000x reference)
//
#include <hip/hip_runtime.h>
#include <hip/hip_bf16.h>
#include <math.h>

// Problem constants
#define LAYERS 4
#define DIM    128
#define NH     8
#define TT     12
#define EE     128
#define BB     2
#define SS     2
#define HD     16
#define HD4    4
#define DFF    512
#define NROWS  (BB*SS*TT*EE)    // 6144 total rows (b,s,t,e)
#define NKROWS (BB*TT*EE)       // 3072 kv rows (s=0 slice only)
#define NPAIR  (TT*(TT+1)/2)    // 78 (tq,tk<=tq) pairs

// ---------------- LayerNorm: one wave per row ----------------
__global__ __launch_bounds__(256) void ln_kernel(const float* __restrict__ x,
                                                 float* __restrict__ y,
                                                 const float* __restrict__ g,
                                                 const float* __restrict__ b) {
    int wave = threadIdx.x >> 6, lane = threadIdx.x & 63;
    int row = blockIdx.x * 4 + wave;
    const float* xp = x + (size_t)row * DIM;
    float2 v = *(const float2*)(xp + lane * 2);
    float s = v.x + v.y;
    float sq = v.x * v.x + v.y * v.y;
    #pragma unroll
    for (int o = 1; o < 64; o <<= 1) {
        s  += __shfl_xor(s, o);
        sq += __shfl_xor(sq, o);
    }
    float mean = s * (1.0f / 128.0f);
    float var  = sq * (1.0f / 128.0f) - mean * mean;
    float rs   = 1.0f / sqrtf(var + 1e-5f);
    float2 gv = *(const float2*)(g + lane * 2);
    float2 bv = *(const float2*)(b + lane * 2);
    float2 o;
    o.x = (v.x - mean) * rs * gv.x + bv.x;
    o.y = (v.y - mean) * rs * gv.y + bv.y;
    *(float2*)(y + (size_t)row * DIM + lane * 2) = o;
}

// ---------------- Generic tiled GEMM: C[M,N] = epi(A[M,K] @ W[N,K]^T + bias) ----
// EPI: 0 = store, 1 = C += (residual add in place), 2 = gelu(exact) store
// GATHER: A row r (compact kv index, M=3072) maps to global row r + (r/1536)*1536
template<int EPI, bool GATHER>
__global__ __launch_bounds__(256) void gemm_kernel(const float* __restrict__ A,
                                                   const float* __restrict__ W,
                                                   const float* __restrict__ bias,
                                                   float* __restrict__ C,
                                                   int M, int N, int K) {
    __shared__ float As[32][36];   // pad 36: float4-aligned, conflict-free
    __shared__ float Ws[32][36];
    int tid = threadIdx.x;
    int tx = tid & 15, ty = tid >> 4;
    int r0 = blockIdx.y << 5, c0 = blockIdx.x << 5;
    int lm = tid >> 3, lk = (tid & 7) << 2;
    int ar = r0 + lm;
    if (GATHER) ar += (ar / 1536) * 1536;
    const float* Ap = A + (size_t)ar * K + lk;
    const float* Wp = W + (size_t)(c0 + lm) * K + lk;
    float a00 = 0.f, a01 = 0.f, a10 = 0.f, a11 = 0.f;
    for (int k0 = 0; k0 < K; k0 += 32) {
        float4 av = *(const float4*)(Ap + k0);
        float4 wv = *(const float4*)(Wp + k0);
        *(float4*)&As[lm][lk] = av;
        *(float4*)&Ws[lm][lk] = wv;
        __syncthreads();
        #pragma unroll
        for (int kk = 0; kk < 32; kk += 4) {
            float4 x0 = *(const float4*)&As[ty][kk];
            float4 x1 = *(const float4*)&As[ty + 16][kk];
            float4 y0 = *(const float4*)&Ws[tx][kk];
            float4 y1 = *(const float4*)&Ws[tx + 16][kk];
            a00 += x0.x*y0.x + x0.y*y0.y + x0.z*y0.z + x0.w*y0.w;
            a01 += x0.x*y1.x + x0.y*y1.y + x0.z*y1.z + x0.w*y1.w;
            a10 += x1.x*y0.x + x1.y*y0.y + x1.z*y0.z + x1.w*y0.w;
            a11 += x1.x*y1.x + x1.y*y1.y + x1.z*y1.z + x1.w*y1.w;
        }
        __syncthreads();
    }
    int r = r0 + ty, c = c0 + tx;
    float b0 = bias[c], b1 = bias[c + 16];
    float v00 = a00 + b0, v01 = a01 + b1, v10 = a10 + b0, v11 = a11 + b1;
    if (EPI == 2) {
        v00 = 0.5f * v00 * (1.0f + erff(v00 * 0.70710678118654752f));
        v01 = 0.5f * v01 * (1.0f + erff(v01 * 0.70710678118654752f));
        v10 = 0.5f * v10 * (1.0f + erff(v10 * 0.70710678118654752f));
        v11 = 0.5f * v11 * (1.0f + erff(v11 * 0.70710678118654752f));
    }
    size_t i00 = (size_t)r * N + c;
    size_t i10 = (size_t)(r + 16) * N + c;
    if (EPI == 1) {
        C[i00]      += v00; C[i00 + 16] += v01;
        C[i10]      += v10; C[i10 + 16] += v11;
    } else {
        C[i00]      = v00;  C[i00 + 16] = v01;
        C[i10]      = v10;  C[i10 + 16] = v11;
    }
}

// ---------------- RoPE in place on q (6144 rows) and k (3072 compact rows) -----
// theta = [1, 1e-4, 1e-4, 1e-4]  (ROPE_SCALE ** floor(-a/HD/2) for a=0,2,4,6)
__global__ __launch_bounds__(256) void rope_kernel(float* __restrict__ qb,
                                                   float* __restrict__ kb) {
    int idx = blockIdx.x * 256 + threadIdx.x;
    const int NQ = NROWS * NH * HD4;   // 196608
    float* p;
    int n, rem;
    if (idx < NQ) {
        p = qb; n = idx >> 5; rem = idx & 31;
    } else {
        idx -= NQ;
        if (idx >= NKROWS * NH * HD4) return;
        p = kb; n = idx >> 5; rem = idx & 31;
    }
    int h = rem >> 2, i = rem & 3;
    int t = (n / EE) % TT;
    float theta = (i == 0) ? 1.0f : 1e-4f;
    float ang = (float)t * theta;
    float sn = sinf(ang), cs = cosf(ang);
    size_t base = (size_t)n * DIM + h * HD + i;
    float xl = p[base], xr = p[base + HD4];
    p[base]       = xl * cs + xr * sn;
    p[base + HD4] = xr * cs - xl * sn;
}

// ---------------- Attention, flash split-K partials ----------------
// grid (NPAIR, NH, BB*SS), block 128 (one query e per thread).
// Each block: queries (b,s,tq,*) x keys (b,tk,*): exactly 128 keys.
// part layout: [bs][h][pair][e][18] = {m, l, acc[16]}
__global__ __launch_bounds__(128) void attn_partial_kernel(const float* __restrict__ q,
                                                           const float* __restrict__ k,
                                                           const float* __restrict__ v,
                                                           float* __restrict__ part) {
    int p = blockIdx.x, h = blockIdx.y, bs = blockIdx.z;
    int b = bs >> 1, s = bs & 1;
    int tq = 0, base = 0;
    while (base + tq + 1 <= p) { base += tq + 1; ++tq; }
    int tk = p - base;
    int e = threadIdx.x;
    int nq = ((b * SS + s) * TT + tq) * EE + e;
    const float* qp = q + (size_t)nq * DIM + h * HD;
    float qv[HD];
    #pragma unroll
    for (int d = 0; d < HD; ++d) qv[d] = qp[d] * 0.25f;   // fold HD^-0.5
    const float* kbase = k + ((size_t)(b * TT + tk) * EE) * DIM + h * HD;
    const float* vbase = v + ((size_t)(b * TT + tk) * EE) * DIM + h * HD;
    float m = -3e38f, l = 0.f;
    float acc[HD];
    #pragma unroll
    for (int d = 0; d < HD; ++d) acc[d] = 0.f;
    for (int j0 = 0; j0 < EE; j0 += 8) {
        float sc[8];
        #pragma unroll
        for (int jj = 0; jj < 8; ++jj) {
            const float* kj = kbase + (size_t)(j0 + jj) * DIM;  // wave-uniform
            float d0 = 0.f;
            #pragma unroll
            for (int d = 0; d < HD; ++d) d0 += qv[d] * kj[d];
            sc[jj] = d0;
        }
        float cm = sc[0];
        #pragma unroll
        for (int jj = 1; jj < 8; ++jj) cm = fmaxf(cm, sc[jj]);
        float mn = fmaxf(m, cm);
        float corr = __expf(m - mn);
        m = mn;
        l *= corr;
        #pragma unroll
        for (int d = 0; d < HD; ++d) acc[d] *= corr;
        #pragma unroll
        for (int jj = 0; jj < 8; ++jj) {
            float pe = __expf(sc[jj] - mn);
            l += pe;
            const float* vj = vbase + (size_t)(j0 + jj) * DIM;  // wave-uniform
            #pragma unroll
            for (int d = 0; d < HD; ++d) acc[d] += pe * vj[d];
        }
    }
    float* pp = part + ((((size_t)bs * NH + h) * NPAIR + p) * EE + e) * 18;
    pp[0] = m; pp[1] = l;
    #pragma unroll
    for (int d = 0; d < HD; ++d) pp[2 + d] = acc[d];
}

// ---------------- Attention combine: merge partials over tk ----------------
// grid (TT, NH, BB*SS), block 128
__global__ __launch_bounds__(128) void attn_combine_kernel(const float* __restrict__ part,
                                                           float* __restrict__ att) {
    int tq = blockIdx.x, h = blockIdx.y, bs = blockIdx.z;
    int e = threadIdx.x;
    int base = tq * (tq + 1) / 2;
    float m = -3e38f, l = 0.f;
    float acc[HD];
    #pragma unroll
    for (int d = 0; d < HD; ++d) acc[d] = 0.f;
    for (int tk = 0; tk <= tq; ++tk) {
        const float* pp = part + ((((size_t)bs * NH + h) * NPAIR + base + tk) * EE + e) * 18;
        float mi = pp[0], li = pp[1];
        float mn = fmaxf(m, mi);
        float c0 = __expf(m - mn), c1 = __expf(mi - mn);
        l = l * c0 + li * c1;
        #pragma unroll
        for (int d = 0; d < HD; ++d) acc[d] = acc[d] * c0 + pp[2 + d] * c1;
        m = mn;
    }
    int b = bs >> 1, s = bs & 1;
    int nq = ((b * SS + s) * TT + tq) * EE + e;
    float inv = 1.0f / l;
    float* op = att + (size_t)nq * DIM + h * HD;
    #pragma unroll
    for (int d = 0; d < HD; ++d) op[d] = acc[d] * inv;
}

// ---------------- Final: out[n] = dot(x[n,:], Wf) + bf ----------------
__global__ __launch_bounds__(256) void final_kernel(const float* __restrict__ x,
                                                    const float* __restrict__ Wf,
                                                    const float* __restrict__ bf,
                                                    float* __restrict__ out) {
    int wave = threadIdx.x >> 6, lane = threadIdx.x & 63;
    int row = blockIdx.x * 4 + wave;
    float2 xv = *(const float2*)(x + (size_t)row * DIM + lane * 2);
    float2 wv = *(const float2*)(Wf + lane * 2);
    float s = xv.x * wv.x + xv.y * wv.y;
    #pragma unroll
    for (int o = 1; o < 64; o <<= 1) s += __shfl_xor(s, o);
    if (lane == 0) out[row] = s + bf[0];
}

// ---------------- Launch ----------------
extern "C" void kernel_launch(void* const* d_in, const int* in_sizes, int n_in,
                              void* d_out, int out_size, void* d_ws, size_t ws_size,
                              hipStream_t stream) {
    const float* x   = (const float*)d_in[0];
    const float* Wq  = (const float*)d_in[1];
    const float* bq  = (const float*)d_in[2];
    const float* Wk  = (const float*)d_in[3];
    const float* bk  = (const float*)d_in[4];
    const float* Wv  = (const float*)d_in[5];
    const float* bv  = (const float*)d_in[6];
    const float* Wo  = (const float*)d_in[7];
    const float* bo  = (const float*)d_in[8];
    const float* W1  = (const float*)d_in[9];
    const float* b1  = (const float*)d_in[10];
    const float* W2  = (const float*)d_in[11];
    const float* b2  = (const float*)d_in[12];
    const float* g1  = (const float*)d_in[13];
    const float* bn1 = (const float*)d_in[14];
    const float* g2  = (const float*)d_in[15];
    const float* bn2 = (const float*)d_in[16];
    const float* Wf  = (const float*)d_in[17];
    const float* bf  = (const float*)d_in[18];
    float* out = (float*)d_out;

    // workspace layout (floats); needs ~35.6 MB
    float* ws      = (float*)d_ws;
    float* xcur    = ws;                 // 786432
    float* x2      = ws + 786432;        // 786432 (also reused as att)
    float* qb      = ws + 1572864;       // 786432
    float* kb      = ws + 2359296;       // 393216
    float* vb      = ws + 2752512;       // 393216
    float* scratch = ws + 3145728;       // max(part 5750784, hbuf 3145728)

    hipMemcpyAsync(xcur, x, (size_t)NROWS * DIM * sizeof(float),
                   hipMemcpyDeviceToDevice, stream);

    for (int i = 0; i < LAYERS; ++i) {
        const float* Wqi = Wq + (size_t)i * DIM * DIM;
        const float* Wki = Wk + (size_t)i * DIM * DIM;
        const float* Wvi = Wv + (size_t)i * DIM * DIM;
        const float* Woi = Wo + (size_t)i * DIM * DIM;
        const float* W1i = W1 + (size_t)i * DFF * DIM;
        const float* W2i = W2 + (size_t)i * DIM * DFF;
        const float* bqi = bq + i * DIM;
        const float* bki = bk + i * DIM;
        const float* bvi = bv + i * DIM;
        const float* boi = bo + i * DIM;
        const float* b1i = b1 + i * DFF;
        const float* b2i = b2 + i * DIM;

        // LN1
        ln_kernel<<<NROWS / 4, 256, 0, stream>>>(xcur, x2, g1 + i * DIM, bn1 + i * DIM);
        // Q/K/V projections (K,V only from s=0 slice via GATHER)
        gemm_kernel<0, false><<<dim3(DIM / 32, NROWS / 32), 256, 0, stream>>>(
            x2, Wqi, bqi, qb, NROWS, DIM, DIM);
        gemm_kernel<0, true><<<dim3(DIM / 32, NKROWS / 32), 256, 0, stream>>>(
            x2, Wki, bki, kb, NKROWS, DIM, DIM);
        gemm_kernel<0, true><<<dim3(DIM / 32, NKROWS / 32), 256, 0, stream>>>(
            x2, Wvi, bvi, vb, NKROWS, DIM, DIM);
        // RoPE on q and k
        rope_kernel<<<(NROWS + NKROWS) * NH * HD4 / 256, 256, 0, stream>>>(qb, kb);
        // attention
        attn_partial_kernel<<<dim3(NPAIR, NH, BB * SS), 128, 0, stream>>>(qb, kb, vb, scratch);
        attn_combine_kernel<<<dim3(TT, NH, BB * SS), 128, 0, stream>>>(scratch, x2);
        // out-proj + residual into xcur
        gemm_kernel<1, false><<<dim3(DIM / 32, NROWS / 32), 256, 0, stream>>>(
            x2, Woi, boi, xcur, NROWS, DIM, DIM);
        // LN2
        ln_kernel<<<NROWS / 4, 256, 0, stream>>>(xcur, x2, g2 + i * DIM, bn2 + i * DIM);
        // FFN
        gemm_kernel<2, false><<<dim3(DFF / 32, NROWS / 32), 256, 0, stream>>>(
            x2, W1i, b1i, scratch, NROWS, DFF, DIM);
        gemm_kernel<1, false><<<dim3(DIM / 32, NROWS / 32), 256, 0, stream>>>(
            scratch, W2i, b2i, xcur, NROWS, DIM, DFF);
    }
    final_kernel<<<NROWS / 4, 256, 0, stream>>>(xcur, Wf, bf, out);
}

// Round 2
// 452.321 us; speedup vs baseline: 1.6506x; 1.6506x over previous
//
#include <hip/hip_runtime.h>
#include <hip/hip_bf16.h>
#include <math.h>

#define LAYERS 4
#define DIM    128
#define NH     8
#define TT     12
#define EE     128
#define BB     2
#define SS     2
#define HD     16
#define DFF    512
#define NROWS  (BB*SS*TT*EE)    // 6144
#define NKROWS (BB*TT*EE)       // 3072 (s=0 slice, compact)

typedef __attribute__((ext_vector_type(8))) short bf16x8;
typedef __attribute__((ext_vector_type(4))) short short4v;
typedef __attribute__((ext_vector_type(4))) float f32x4;

#define MFMA16 __builtin_amdgcn_mfma_f32_16x16x32_bf16

__device__ __forceinline__ unsigned short f2bf(float f) {
    union { float f; unsigned u; } x; x.f = f;
    unsigned r = x.u + 0x7fffu + ((x.u >> 16) & 1u);
    return (unsigned short)(r >> 16);
}

// ---------------- weight fp32 -> bf16 conversion (once per launch) ----------
// wbuf layout (shorts): wq[0..65536) wk[..131072) wv[..196608) wo[..262144)
//                       w1[..524288) w2[..786432)
__global__ __launch_bounds__(256) void wconv_kernel(const float* __restrict__ Wq,
        const float* __restrict__ Wk, const float* __restrict__ Wv,
        const float* __restrict__ Wo, const float* __restrict__ W1,
        const float* __restrict__ W2, short* __restrict__ wbuf) {
    int idx = (blockIdx.x * 256 + threadIdx.x) * 4;
    const float* src; int off;
    if      (idx < 65536)  { src = Wq; off = idx; }
    else if (idx < 131072) { src = Wk; off = idx - 65536; }
    else if (idx < 196608) { src = Wv; off = idx - 131072; }
    else if (idx < 262144) { src = Wo; off = idx - 196608; }
    else if (idx < 524288) { src = W1; off = idx - 262144; }
    else                   { src = W2; off = idx - 524288; }
    float4 v = *(const float4*)(src + off);
    short4v o = { (short)f2bf(v.x), (short)f2bf(v.y), (short)f2bf(v.z), (short)f2bf(v.w) };
    *(short4v*)(wbuf + idx) = o;
}

// ---------------- LayerNorm: fp32 in, bf16 out; one wave per row -----------
__global__ __launch_bounds__(256) void ln_kernel(const float* __restrict__ x,
                                                 short* __restrict__ y,
                                                 const float* __restrict__ g,
                                                 const float* __restrict__ b) {
    int wave = threadIdx.x >> 6, lane = threadIdx.x & 63;
    int row = blockIdx.x * 4 + wave;
    const float* xp = x + (size_t)row * DIM;
    float2 v = *(const float2*)(xp + lane * 2);
    float s = v.x + v.y, sq = v.x * v.x + v.y * v.y;
    #pragma unroll
    for (int o = 1; o < 64; o <<= 1) { s += __shfl_xor(s, o); sq += __shfl_xor(sq, o); }
    float mean = s * (1.0f / 128.0f);
    float var = sq * (1.0f / 128.0f) - mean * mean;
    float rs = 1.0f / sqrtf(var + 1e-5f);
    float2 gv = *(const float2*)(g + lane * 2);
    float2 bv = *(const float2*)(b + lane * 2);
    float ox = (v.x - mean) * rs * gv.x + bv.x;
    float oy = (v.y - mean) * rs * gv.y + bv.y;
    unsigned u = (unsigned)f2bf(ox) | ((unsigned)f2bf(oy) << 16);
    *(unsigned*)(&y[(size_t)row * 128 + lane * 2]) = u;
}

// ---------------- shared GEMM mainloop: 64x64 tile, 4 waves, 2x2 frags -----
__device__ __forceinline__ void gemm_core(const short* __restrict__ Ab,
                                          const short* __restrict__ Wb,
                                          int K, f32x4 acc[2][2]) {
    #pragma unroll 4
    for (int k0 = 0; k0 < K; k0 += 32) {
        bf16x8 a0 = *(const bf16x8*)(Ab + k0);
        bf16x8 a1 = *(const bf16x8*)(Ab + (size_t)16 * K + k0);
        bf16x8 b0 = *(const bf16x8*)(Wb + k0);
        bf16x8 b1 = *(const bf16x8*)(Wb + (size_t)16 * K + k0);
        acc[0][0] = MFMA16(a0, b0, acc[0][0], 0, 0, 0);
        acc[0][1] = MFMA16(a0, b1, acc[0][1], 0, 0, 0);
        acc[1][0] = MFMA16(a1, b0, acc[1][0], 0, 0, 0);
        acc[1][1] = MFMA16(a1, b1, acc[1][1], 0, 0, 0);
    }
}

// ---------------- fused QKV projection + RoPE + V-transpose ----------------
// grid (2, 96, 3): z=0 Q (M=6144) -> qb (rope, *0.25); z=1 K (M=3072 compact)
// -> kb (rope); z=2 V -> vt[b][h][d][k] transposed.
__global__ __launch_bounds__(256) void qkv_kernel(const short* __restrict__ x2b,
        const short* __restrict__ wbuf, const float* __restrict__ bq,
        const float* __restrict__ bk, const float* __restrict__ bv, int layer,
        short* __restrict__ qb, short* __restrict__ kb, short* __restrict__ vt) {
    int z = blockIdx.z, by = blockIdx.y, bx = blockIdx.x;
    if (z > 0 && by >= 48) return;
    const short* Wz = wbuf + (z == 0 ? 0 : z == 1 ? 65536 : 131072) + layer * 16384;
    const float* bz = (z == 0 ? bq : z == 1 ? bk : bv) + layer * 128;
    int r0 = by * 64, c0 = bx * 64;
    int gadd = (z > 0) ? (r0 / 1536) * 1536 : 0;   // compact kv row -> global row
    int tid = threadIdx.x, wv = tid >> 6, lid = tid & 63, q15 = lid & 15, g = lid >> 4;
    int wr = wv >> 1, wc = wv & 1;
    const short* Ab = x2b + (size_t)(r0 + gadd + wr * 32 + q15) * 128 + g * 8;
    const short* Wb = Wz + (size_t)(c0 + wc * 32 + q15) * 128 + g * 8;
    f32x4 acc[2][2] = {{{0,0,0,0},{0,0,0,0}},{{0,0,0,0},{0,0,0,0}}};
    gemm_core(Ab, Wb, 128, acc);
    int t = (by >> 1) % 12;            // block-uniform t (64-row tiles)
    if (z < 2) {
        short* dst = z ? kb : qb;
        float sc = z ? 1.0f : 0.25f;   // fold HD^-0.5 into q
        int cc = q15, i4 = cc & 3;
        float theta = (i4 == 0) ? 1.0f : 1e-4f;
        float ang = (float)t * theta;
        float sn = sinf(ang), cs = cosf(ang);
        #pragma unroll
        for (int mi = 0; mi < 2; ++mi)
        #pragma unroll
        for (int ni = 0; ni < 2; ++ni) {
            int c = c0 + wc * 32 + ni * 16 + q15;
            float bb = bz[c];
            #pragma unroll
            for (int j = 0; j < 4; ++j) {
                float v = acc[mi][ni][j] + bb;
                float pv = __shfl_xor(v, 4);   // partner column c^4
                float vo = (cc < 4) ? (v * cs + pv * sn)
                         : (cc < 8) ? (v * cs - pv * sn) : v;
                vo *= sc;
                int r = r0 + wr * 32 + mi * 16 + g * 4 + j;
                dst[(size_t)r * 128 + c] = (short)f2bf(vo);
            }
        }
    } else {
        #pragma unroll
        for (int mi = 0; mi < 2; ++mi)
        #pragma unroll
        for (int ni = 0; ni < 2; ++ni) {
            int c = c0 + wc * 32 + ni * 16 + q15;
            float bb = bz[c];
            int rb = r0 + wr * 32 + mi * 16 + g * 4;       // compact row base
            int bidx = rb / 1536, kk = rb % 1536;
            short4v o;
            #pragma unroll
            for (int j = 0; j < 4; ++j) o[j] = (short)f2bf(acc[mi][ni][j] + bb);
            *(short4v*)(vt + ((size_t)(bidx * 8 + (c >> 4)) * 16 + (c & 15)) * 1536 + kk) = o;
        }
    }
}

// ---------------- fused flash attention ------------------------------------
// grid (12, 8, 4) = (tq, h, b*2+s); block 512 = 8 waves x 16 queries.
// S^T = K @ Q^T via MFMA (d zero-padded 16->32); online softmax; P frag
// rearranged by shfl to feed PV MFMA over 32 keys.
__global__ __launch_bounds__(512) void attn_kernel(const short* __restrict__ qb,
        const short* __restrict__ kb, const short* __restrict__ vt,
        short* __restrict__ attb) {
    int tq = blockIdx.x, h = blockIdx.y, bs = blockIdx.z, b = bs >> 1;
    int wv = threadIdx.x >> 6, lid = threadIdx.x & 63, q15 = lid & 15, g = lid >> 4;
    int qrow0 = (bs * 12 + tq) * 128 + wv * 16;
    bf16x8 qf = {0,0,0,0,0,0,0,0};
    if (g < 2) qf = *(const bf16x8*)(qb + (size_t)(qrow0 + q15) * 128 + h * 16 + g * 8);
    const short* kbase = kb + (size_t)(b * 1536) * 128 + h * 16 + g * 8;
    const short* vbase = vt + ((size_t)(b * 8 + h) * 16 + q15) * 1536;
    f32x4 acc = {0, 0, 0, 0};
    float m = -1e30f, l = 0.f;
    int nch = (tq + 1) * 4;            // 32-key chunks
    for (int c = 0; c < nch; ++c) {
        bf16x8 a0 = {0,0,0,0,0,0,0,0}, a1 = {0,0,0,0,0,0,0,0};
        if (g < 2) {
            const short* kp = kbase + (size_t)(c * 32 + q15) * 128;
            a0 = *(const bf16x8*)(kp);
            a1 = *(const bf16x8*)(kp + 16 * 128);
        }
        f32x4 z4 = {0, 0, 0, 0};
        f32x4 s0 = MFMA16(a0, qf, z4, 0, 0, 0);   // S^T[key][q], keys c*32+0..15
        f32x4 s1 = MFMA16(a1, qf, z4, 0, 0, 0);   // keys c*32+16..31
        float cm = fmaxf(fmaxf(fmaxf(s0[0], s0[1]), fmaxf(s0[2], s0[3])),
                         fmaxf(fmaxf(s1[0], s1[1]), fmaxf(s1[2], s1[3])));
        cm = fmaxf(cm, __shfl_xor(cm, 16));
        cm = fmaxf(cm, __shfl_xor(cm, 32));
        float mn = fmaxf(m, cm);
        float corr = __expf(m - mn);
        m = mn;
        float p0[4], p1[4]; float ps = 0.f;
        #pragma unroll
        for (int j = 0; j < 4; ++j) {
            p0[j] = __expf(s0[j] - mn);
            p1[j] = __expf(s1[j] - mn);
            ps += p0[j] + p1[j];
        }
        ps += __shfl_xor(ps, 16);
        ps += __shfl_xor(ps, 32);      // full 32-key chunk sum per query
        l = l * corr + ps;
        #pragma unroll
        for (int r = 0; r < 4; ++r) { float cr = __shfl(corr, g * 4 + r); acc[r] *= cr; }
        // rearrange S^T frags -> PV A-frag: lane(g,q) needs P[q][8g+j]
        int srcA = ((g & 1) << 5) + q15;
        bool sel = g >= 2;
        bf16x8 pf;
        #pragma unroll
        for (int j = 0; j < 4; ++j) {
            float u0 = __shfl(p0[j], srcA),      u1 = __shfl(p1[j], srcA);
            float w0 = __shfl(p0[j], srcA + 16), w1 = __shfl(p1[j], srcA + 16);
            pf[j]     = (short)f2bf(sel ? u1 : u0);
            pf[j + 4] = (short)f2bf(sel ? w1 : w0);
        }
        bf16x8 vf = *(const bf16x8*)(vbase + c * 32 + g * 8);
        acc = MFMA16(pf, vf, acc, 0, 0, 0);
    }
    float linv = 1.0f / l;
    #pragma unroll
    for (int r = 0; r < 4; ++r) {
        float lr = __shfl(linv, g * 4 + r);
        attb[(size_t)(qrow0 + g * 4 + r) * 128 + h * 16 + q15] = (short)f2bf(acc[r] * lr);
    }
}

// ---------------- GEMM + residual add into fp32 C (N=128) ------------------
__global__ __launch_bounds__(256) void res_gemm(const short* __restrict__ A,
        const short* __restrict__ W, const float* __restrict__ bias,
        float* __restrict__ C, int K) {
    int by = blockIdx.y, bx = blockIdx.x;
    int r0 = by * 64, c0 = bx * 64;
    int tid = threadIdx.x, wv = tid >> 6, lid = tid & 63, q15 = lid & 15, g = lid >> 4;
    int wr = wv >> 1, wc = wv & 1;
    const short* Ab = A + (size_t)(r0 + wr * 32 + q15) * K + g * 8;
    const short* Wb = W + (size_t)(c0 + wc * 32 + q15) * K + g * 8;
    f32x4 acc[2][2] = {{{0,0,0,0},{0,0,0,0}},{{0,0,0,0},{0,0,0,0}}};
    gemm_core(Ab, Wb, K, acc);
    #pragma unroll
    for (int mi = 0; mi < 2; ++mi)
    #pragma unroll
    for (int ni = 0; ni < 2; ++ni) {
        int c = c0 + wc * 32 + ni * 16 + q15;
        float bb = bias[c];
        #pragma unroll
        for (int j = 0; j < 4; ++j) {
            int r = r0 + wr * 32 + mi * 16 + g * 4 + j;
            C[(size_t)r * 128 + c] += acc[mi][ni][j] + bb;
        }
    }
}

// ---------------- GEMM + exact GELU -> bf16 (N=512, K=128) -----------------
__global__ __launch_bounds__(256) void gelu_gemm(const short* __restrict__ A,
        const short* __restrict__ W, const float* __restrict__ bias,
        short* __restrict__ H) {
    int by = blockIdx.y, bx = blockIdx.x;
    int r0 = by * 64, c0 = bx * 64;
    int tid = threadIdx.x, wv = tid >> 6, lid = tid & 63, q15 = lid & 15, g = lid >> 4;
    int wr = wv >> 1, wc = wv & 1;
    const short* Ab = A + (size_t)(r0 + wr * 32 + q15) * 128 + g * 8;
    const short* Wb = W + (size_t)(c0 + wc * 32 + q15) * 128 + g * 8;
    f32x4 acc[2][2] = {{{0,0,0,0},{0,0,0,0}},{{0,0,0,0},{0,0,0,0}}};
    gemm_core(Ab, Wb, 128, acc);
    #pragma unroll
    for (int mi = 0; mi < 2; ++mi)
    #pragma unroll
    for (int ni = 0; ni < 2; ++ni) {
        int c = c0 + wc * 32 + ni * 16 + q15;
        float bb = bias[c];
        #pragma unroll
        for (int j = 0; j < 4; ++j) {
            int r = r0 + wr * 32 + mi * 16 + g * 4 + j;
            float v = acc[mi][ni][j] + bb;
            v = 0.5f * v * (1.0f + erff(v * 0.70710678118654752f));
            H[(size_t)r * 512 + c] = (short)f2bf(v);
        }
    }
}

// ---------------- Final: out[n] = dot(x[n,:], Wf) + bf ----------------
__global__ __launch_bounds__(256) void final_kernel(const float* __restrict__ x,
        const float* __restrict__ Wf, const float* __restrict__ bf,
        float* __restrict__ out) {
    int wave = threadIdx.x >> 6, lane = threadIdx.x & 63;
    int row = blockIdx.x * 4 + wave;
    float2 xv = *(const float2*)(x + (size_t)row * DIM + lane * 2);
    float2 wv = *(const float2*)(Wf + lane * 2);
    float s = xv.x * wv.x + xv.y * wv.y;
    #pragma unroll
    for (int o = 1; o < 64; o <<= 1) s += __shfl_xor(s, o);
    if (lane == 0) out[row] = s + bf[0];
}

// ---------------- Launch ----------------
extern "C" void kernel_launch(void* const* d_in, const int* in_sizes, int n_in,
                              void* d_out, int out_size, void* d_ws, size_t ws_size,
                              hipStream_t stream) {
    const float* x   = (const float*)d_in[0];
    const float* Wq  = (const float*)d_in[1];
    const float* bq  = (const float*)d_in[2];
    const float* Wk  = (const float*)d_in[3];
    const float* bk  = (const float*)d_in[4];
    const float* Wv  = (const float*)d_in[5];
    const float* bv  = (const float*)d_in[6];
    const float* Wo  = (const float*)d_in[7];
    const float* bo  = (const float*)d_in[8];
    const float* W1  = (const float*)d_in[9];
    const float* b1  = (const float*)d_in[10];
    const float* W2  = (const float*)d_in[11];
    const float* b2  = (const float*)d_in[12];
    const float* g1  = (const float*)d_in[13];
    const float* bn1 = (const float*)d_in[14];
    const float* g2  = (const float*)d_in[15];
    const float* bn2 = (const float*)d_in[16];
    const float* Wf  = (const float*)d_in[17];
    const float* bf  = (const float*)d_in[18];
    float* out = (float*)d_out;

    char* wsb = (char*)d_ws;
    float* xcur = (float*)(wsb + 0);           // 3 MB fp32
    short* x2b  = (short*)(wsb + 3145728);     // 1.5 MB bf16
    short* qb   = (short*)(wsb + 4718592);     // 1.5 MB
    short* kb   = (short*)(wsb + 6291456);     // 0.75 MB
    short* vt   = (short*)(wsb + 7077888);     // 0.75 MB  [b][h][d][1536]
    short* attb = (short*)(wsb + 7864320);     // 1.5 MB
    short* hb   = (short*)(wsb + 9437184);     // 6 MB
    short* wbuf = (short*)(wsb + 15728640);    // 1.5 MB

    hipMemcpyAsync(xcur, x, (size_t)NROWS * DIM * sizeof(float),
                   hipMemcpyDeviceToDevice, stream);
    wconv_kernel<<<768, 256, 0, stream>>>(Wq, Wk, Wv, Wo, W1, W2, wbuf);

    for (int i = 0; i < LAYERS; ++i) {
        const short* wob = wbuf + 196608 + i * 16384;
        const short* w1b = wbuf + 262144 + i * 65536;
        const short* w2b = wbuf + 524288 + i * 65536;

        ln_kernel<<<NROWS / 4, 256, 0, stream>>>(xcur, x2b, g1 + i * DIM, bn1 + i * DIM);
        qkv_kernel<<<dim3(2, 96, 3), 256, 0, stream>>>(x2b, wbuf, bq, bk, bv, i, qb, kb, vt);
        attn_kernel<<<dim3(12, 8, 4), 512, 0, stream>>>(qb, kb, vt, attb);
        res_gemm<<<dim3(2, 96), 256, 0, stream>>>(attb, wob, bo + i * DIM, xcur, 128);
        ln_kernel<<<NROWS / 4, 256, 0, stream>>>(xcur, x2b, g2 + i * DIM, bn2 + i * DIM);
        gelu_gemm<<<dim3(8, 96), 256, 0, stream>>>(x2b, w1b, b1 + i * DFF, hb);
        res_gemm<<<dim3(2, 96), 256, 0, stream>>>(hb, w2b, b2 + i * DIM, xcur, 512);
    }
    final_kernel<<<NROWS / 4, 256, 0, stream>>>(xcur, Wf, bf, out);
}

// Round 3
// 443.667 us; speedup vs baseline: 1.6828x; 1.0195x over previous
//
#include <hip/hip_runtime.h>
#include <hip/hip_bf16.h>
#include <math.h>

#define LAYERS 4
#define DIM    128
#define NH     8
#define TT     12
#define EE     128
#define BB     2
#define SS     2
#define HD     16
#define DFF    512
#define NROWS  (BB*SS*TT*EE)    // 6144
#define NKROWS (BB*TT*EE)       // 3072 (s=0 slice, compact)

typedef __attribute__((ext_vector_type(8)))  short bf16x8;
typedef __attribute__((ext_vector_type(4)))  short short4v;
typedef __attribute__((ext_vector_type(4)))  float f32x4;
typedef __attribute__((ext_vector_type(16))) float f32x16;

#define MFMA32 __builtin_amdgcn_mfma_f32_32x32x16_bf16

__device__ __forceinline__ unsigned short f2bf(float f) {
    union { float f; unsigned u; } x; x.f = f;
    unsigned r = x.u + 0x7fffu + ((x.u >> 16) & 1u);
    return (unsigned short)(r >> 16);
}

__device__ __forceinline__ unsigned cvtpk(float a, float b) {
    unsigned r;
    asm("v_cvt_pk_bf16_f32 %0, %1, %2" : "=v"(r) : "v"(a), "v"(b));
    return r;
}

union U8 { unsigned u[4]; bf16x8 v; };

// ---------------- weight fp32 -> bf16 conversion (once per launch) ----------
__global__ __launch_bounds__(256) void wconv_kernel(const float* __restrict__ Wq,
        const float* __restrict__ Wk, const float* __restrict__ Wv,
        const float* __restrict__ Wo, const float* __restrict__ W1,
        const float* __restrict__ W2, short* __restrict__ wbuf) {
    int idx = (blockIdx.x * 256 + threadIdx.x) * 4;
    const float* src; int off;
    if      (idx < 65536)  { src = Wq; off = idx; }
    else if (idx < 131072) { src = Wk; off = idx - 65536; }
    else if (idx < 196608) { src = Wv; off = idx - 131072; }
    else if (idx < 262144) { src = Wo; off = idx - 196608; }
    else if (idx < 524288) { src = W1; off = idx - 262144; }
    else                   { src = W2; off = idx - 524288; }
    float4 v = *(const float4*)(src + off);
    short4v o = { (short)f2bf(v.x), (short)f2bf(v.y), (short)f2bf(v.z), (short)f2bf(v.w) };
    *(short4v*)(wbuf + idx) = o;
}

// ---------------- LayerNorm: fp32 in, bf16 out; one wave per row -----------
__global__ __launch_bounds__(256) void ln_kernel(const float* __restrict__ x,
                                                 short* __restrict__ y,
                                                 const float* __restrict__ g,
                                                 const float* __restrict__ b) {
    int wave = threadIdx.x >> 6, lane = threadIdx.x & 63;
    int row = blockIdx.x * 4 + wave;
    const float* xp = x + (size_t)row * DIM;
    float2 v = *(const float2*)(xp + lane * 2);
    float s = v.x + v.y, sq = v.x * v.x + v.y * v.y;
    #pragma unroll
    for (int o = 1; o < 64; o <<= 1) { s += __shfl_xor(s, o); sq += __shfl_xor(sq, o); }
    float mean = s * (1.0f / 128.0f);
    float var = sq * (1.0f / 128.0f) - mean * mean;
    float rs = 1.0f / sqrtf(var + 1e-5f);
    float2 gv = *(const float2*)(g + lane * 2);
    float2 bv = *(const float2*)(b + lane * 2);
    float ox = (v.x - mean) * rs * gv.x + bv.x;
    float oy = (v.y - mean) * rs * gv.y + bv.y;
    unsigned u = (unsigned)f2bf(ox) | ((unsigned)f2bf(oy) << 16);
    *(unsigned*)(&y[(size_t)row * 128 + lane * 2]) = u;
}

// ------------- 32x32x16 GEMM core: wave tile 64 rows x 32 cols -------------
// A-frag: lane row=l&31, k=(l>>5)*8+j ; B-frag: col=l&31, k=(l>>5)*8+j
// C: col=l&31, row=(reg&3)+8*(reg>>2)+4*(l>>5)
__device__ __forceinline__ void gemm_core32(const short* __restrict__ Ab,
                                            const short* __restrict__ Wb,
                                            int K, f32x16 acc[2]) {
    #pragma unroll 8
    for (int k0 = 0; k0 < K; k0 += 16) {
        bf16x8 a0 = *(const bf16x8*)(Ab + k0);
        bf16x8 a1 = *(const bf16x8*)(Ab + (size_t)32 * K + k0);
        bf16x8 b  = *(const bf16x8*)(Wb + k0);
        acc[0] = MFMA32(a0, b, acc[0], 0, 0, 0);
        acc[1] = MFMA32(a1, b, acc[1], 0, 0, 0);
    }
}

// ---------------- fused QKV projection + RoPE + V-transpose ----------------
// grid (2, 48, 3), block 256 (4 waves, block tile 128r x 64c).
__global__ __launch_bounds__(256) void qkv_kernel(const short* __restrict__ x2b,
        const short* __restrict__ wbuf, const float* __restrict__ bq,
        const float* __restrict__ bk, const float* __restrict__ bv, int layer,
        short* __restrict__ qb, short* __restrict__ kb, short* __restrict__ vt) {
    int z = blockIdx.z, by = blockIdx.y, bx = blockIdx.x;
    if (z > 0 && by >= 24) return;
    const short* Wz = wbuf + (z == 0 ? 0 : z == 1 ? 65536 : 131072) + layer * 16384;
    const float* bz = (z == 0 ? bq : z == 1 ? bk : bv) + layer * 128;
    int r0 = by * 128, c0 = bx * 64;
    int gadd = (z > 0) ? (by / 12) * 1536 : 0;     // compact kv row -> global row
    int tid = threadIdx.x, wv = tid >> 6, l = tid & 63, l31 = l & 31, hi = l >> 5;
    int wr = wv >> 1, wc = wv & 1;
    const short* Ab = x2b + (size_t)(r0 + gadd + wr * 64 + l31) * 128 + hi * 8;
    const short* Wb = Wz + (size_t)(c0 + wc * 32 + l31) * 128 + hi * 8;
    f32x16 acc[2];
    #pragma unroll
    for (int i = 0; i < 16; ++i) { acc[0][i] = 0.f; acc[1][i] = 0.f; }
    gemm_core32(Ab, Wb, 128, acc);
    int c = c0 + wc * 32 + l31;
    float bb = bz[c];
    int t = by % 12;
    if (z < 2) {
        short* dst = z ? kb : qb;
        float sc = z ? 1.0f : 0.25f;               // fold HD^-0.5 into q
        int cc = c & 15, i4 = c & 3;
        float theta = (i4 == 0) ? 1.0f : 1e-4f;
        float ang = (float)t * theta;
        float sn = sinf(ang), cs = cosf(ang);
        #pragma unroll
        for (int mi = 0; mi < 2; ++mi)
        #pragma unroll
        for (int reg = 0; reg < 16; ++reg) {
            float v = acc[mi][reg] + bb;
            float pv = __shfl_xor(v, 4);           // partner column c^4
            float vo = (cc < 4) ? (v * cs + pv * sn)
                     : (cc < 8) ? (v * cs - pv * sn) : v;
            vo *= sc;
            int r = r0 + wr * 64 + mi * 32 + (reg & 3) + 8 * (reg >> 2) + 4 * hi;
            dst[(size_t)r * 128 + c] = (short)f2bf(vo);
        }
    } else {
        int d = c & 15, hh = c >> 4, bidx = by / 12;
        #pragma unroll
        for (int mi = 0; mi < 2; ++mi)
        #pragma unroll
        for (int rq = 0; rq < 4; ++rq) {           // regs 4rq..4rq+3 -> kk consecutive
            int rcb = r0 + wr * 64 + mi * 32 + 8 * rq + 4 * hi;
            int kk = rcb - bidx * 1536;
            short4v o;
            #pragma unroll
            for (int j = 0; j < 4; ++j) o[j] = (short)f2bf(acc[mi][4 * rq + j] + bb);
            *(short4v*)(vt + ((size_t)(bidx * 8 + hh) * 16 + d) * 1536 + kk) = o;
        }
    }
}

// ---------------- fused flash attention (32x32x16) -------------------------
// grid 384 blocks (tq descending), block 256 = 4 waves x 32 queries.
// S^T = MFMA(K, Q^T): col=query -> lane-uniform softmax state; P^T built via
// cvt_pk + 4x shfl_xor(32); O^T = MFMA(V^T, P^T) keeps col=query.
__global__ __launch_bounds__(256) void attn_kernel(const short* __restrict__ qb,
        const short* __restrict__ kb, const short* __restrict__ vt,
        short* __restrict__ attb) {
    int bid = blockIdx.x;
    int tq = 11 - (bid >> 5);
    int hb = bid & 31, h = hb >> 2, bs = hb & 3, b = bs >> 1;
    int wv = threadIdx.x >> 6, l = threadIdx.x & 63, l31 = l & 31, hi = l >> 5;
    int q0 = (bs * 12 + tq) * 128 + wv * 32;
    bf16x8 qf = *(const bf16x8*)(qb + (size_t)(q0 + l31) * 128 + h * 16 + hi * 8);
    const short* kp = kb + (size_t)(b * 1536 + l31) * 128 + h * 16 + hi * 8;
    const short* vp = vt + ((size_t)(b * 8 + h) * 16 + l31) * 1536 + hi * 8;
    bool vload = l31 < 16;
    f32x16 acc, zv;
    #pragma unroll
    for (int i = 0; i < 16; ++i) { acc[i] = 0.f; zv[i] = 0.f; }
    float m = -1e30f, lsum = 0.f;
    int nch = (tq + 1) * 4;
    for (int c = 0; c < nch; ++c) {
        bf16x8 kf = *(const bf16x8*)(kp + (size_t)c * 32 * 128);
        f32x16 s = MFMA32(kf, qf, zv, 0, 0, 0);    // S^T[key 0..31][q=l31]
        float cm = s[0];
        #pragma unroll
        for (int j = 1; j < 16; ++j) cm = fmaxf(cm, s[j]);
        cm = fmaxf(cm, __shfl_xor(cm, 32));
        float mn = fmaxf(m, cm);
        float corr = __expf(m - mn);
        m = mn;
        float p[16]; float ps = 0.f;
        #pragma unroll
        for (int j = 0; j < 16; ++j) { p[j] = __expf(s[j] - mn); ps += p[j]; }
        ps += __shfl_xor(ps, 32);
        lsum = lsum * corr + ps;
        #pragma unroll
        for (int r = 0; r < 8; ++r) acc[r] *= corr;   // rows>=16 stay 0
        unsigned w0 = cvtpk(p[0],  p[1]),  w1 = cvtpk(p[2],  p[3]);
        unsigned w2 = cvtpk(p[4],  p[5]),  w3 = cvtpk(p[6],  p[7]);
        unsigned w4 = cvtpk(p[8],  p[9]),  w5 = cvtpk(p[10], p[11]);
        unsigned w6 = cvtpk(p[12], p[13]), w7 = cvtpk(p[14], p[15]);
        unsigned t1 = hi ? w0 : w2, t2 = hi ? w1 : w3;
        unsigned t3 = hi ? w4 : w6, t4 = hi ? w5 : w7;
        unsigned x1 = __shfl_xor((int)t1, 32), x2 = __shfl_xor((int)t2, 32);
        unsigned x3 = __shfl_xor((int)t3, 32), x4 = __shfl_xor((int)t4, 32);
        U8 pb1, pb2;
        pb1.u[0] = hi ? x1 : w0;  pb1.u[1] = hi ? x2 : w1;
        pb1.u[2] = hi ? w2 : x1;  pb1.u[3] = hi ? w3 : x2;
        pb2.u[0] = hi ? x3 : w4;  pb2.u[1] = hi ? x4 : w5;
        pb2.u[2] = hi ? w6 : x3;  pb2.u[3] = hi ? w7 : x4;
        bf16x8 vf1, vf2;
        #pragma unroll
        for (int i = 0; i < 8; ++i) { vf1[i] = 0; vf2[i] = 0; }
        if (vload) {
            vf1 = *(const bf16x8*)(vp + c * 32);
            vf2 = *(const bf16x8*)(vp + c * 32 + 16);
        }
        acc = MFMA32(vf1, pb1.v, acc, 0, 0, 0);    // keys c*32+0..15
        acc = MFMA32(vf2, pb2.v, acc, 0, 0, 0);    // keys c*32+16..31
    }
    float linv = 1.0f / lsum;
    short4v o1, o2;
    #pragma unroll
    for (int j = 0; j < 4; ++j) o1[j] = (short)f2bf(acc[j] * linv);
    #pragma unroll
    for (int j = 0; j < 4; ++j) o2[j] = (short)f2bf(acc[4 + j] * linv);
    size_t base = (size_t)(q0 + l31) * 128 + h * 16;
    *(short4v*)(attb + base + 4 * hi) = o1;        // d = 4hi..4hi+3
    *(short4v*)(attb + base + 8 + 4 * hi) = o2;    // d = 8+4hi..+3
}

// ---------------- GEMM + residual add into fp32 C (N=128) ------------------
__global__ __launch_bounds__(256) void res_gemm(const short* __restrict__ A,
        const short* __restrict__ W, const float* __restrict__ bias,
        float* __restrict__ C, int K) {
    int by = blockIdx.y, bx = blockIdx.x;
    int r0 = by * 128, c0 = bx * 64;
    int tid = threadIdx.x, wv = tid >> 6, l = tid & 63, l31 = l & 31, hi = l >> 5;
    int wr = wv >> 1, wc = wv & 1;
    const short* Ab = A + (size_t)(r0 + wr * 64 + l31) * K + hi * 8;
    const short* Wb = W + (size_t)(c0 + wc * 32 + l31) * K + hi * 8;
    f32x16 acc[2];
    #pragma unroll
    for (int i = 0; i < 16; ++i) { acc[0][i] = 0.f; acc[1][i] = 0.f; }
    gemm_core32(Ab, Wb, K, acc);
    int c = c0 + wc * 32 + l31;
    float bb = bias[c];
    #pragma unroll
    for (int mi = 0; mi < 2; ++mi)
    #pragma unroll
    for (int reg = 0; reg < 16; ++reg) {
        int r = r0 + wr * 64 + mi * 32 + (reg & 3) + 8 * (reg >> 2) + 4 * hi;
        C[(size_t)r * 128 + c] += acc[mi][reg] + bb;
    }
}

// ---------------- GEMM + exact GELU -> bf16 (N=512, K=128) -----------------
__global__ __launch_bounds__(256) void gelu_gemm(const short* __restrict__ A,
        const short* __restrict__ W, const float* __restrict__ bias,
        short* __restrict__ H) {
    int by = blockIdx.y, bx = blockIdx.x;
    int r0 = by * 128, c0 = bx * 64;
    int tid = threadIdx.x, wv = tid >> 6, l = tid & 63, l31 = l & 31, hi = l >> 5;
    int wr = wv >> 1, wc = wv & 1;
    const short* Ab = A + (size_t)(r0 + wr * 64 + l31) * 128 + hi * 8;
    const short* Wb = W + (size_t)(c0 + wc * 32 + l31) * 128 + hi * 8;
    f32x16 acc[2];
    #pragma unroll
    for (int i = 0; i < 16; ++i) { acc[0][i] = 0.f; acc[1][i] = 0.f; }
    gemm_core32(Ab, Wb, 128, acc);
    int c = c0 + wc * 32 + l31;
    float bb = bias[c];
    #pragma unroll
    for (int mi = 0; mi < 2; ++mi)
    #pragma unroll
    for (int reg = 0; reg < 16; ++reg) {
        int r = r0 + wr * 64 + mi * 32 + (reg & 3) + 8 * (reg >> 2) + 4 * hi;
        float v = acc[mi][reg] + bb;
        v = 0.5f * v * (1.0f + erff(v * 0.70710678118654752f));
        H[(size_t)r * 512 + c] = (short)f2bf(v);
    }
}

// ---------------- Final: out[n] = dot(x[n,:], Wf) + bf ----------------
__global__ __launch_bounds__(256) void final_kernel(const float* __restrict__ x,
        const float* __restrict__ Wf, const float* __restrict__ bf,
        float* __restrict__ out) {
    int wave = threadIdx.x >> 6, lane = threadIdx.x & 63;
    int row = blockIdx.x * 4 + wave;
    float2 xv = *(const float2*)(x + (size_t)row * DIM + lane * 2);
    float2 wv = *(const float2*)(Wf + lane * 2);
    float s = xv.x * wv.x + xv.y * wv.y;
    #pragma unroll
    for (int o = 1; o < 64; o <<= 1) s += __shfl_xor(s, o);
    if (lane == 0) out[row] = s + bf[0];
}

// ---------------- Launch ----------------
extern "C" void kernel_launch(void* const* d_in, const int* in_sizes, int n_in,
                              void* d_out, int out_size, void* d_ws, size_t ws_size,
                              hipStream_t stream) {
    const float* x   = (const float*)d_in[0];
    const float* Wq  = (const float*)d_in[1];
    const float* bq  = (const float*)d_in[2];
    const float* Wk  = (const float*)d_in[3];
    const float* bk  = (const float*)d_in[4];
    const float* Wv  = (const float*)d_in[5];
    const float* bv  = (const float*)d_in[6];
    const float* Wo  = (const float*)d_in[7];
    const float* bo  = (const float*)d_in[8];
    const float* W1  = (const float*)d_in[9];
    const float* b1  = (const float*)d_in[10];
    const float* W2  = (const float*)d_in[11];
    const float* b2  = (const float*)d_in[12];
    const float* g1  = (const float*)d_in[13];
    const float* bn1 = (const float*)d_in[14];
    const float* g2  = (const float*)d_in[15];
    const float* bn2 = (const float*)d_in[16];
    const float* Wf  = (const float*)d_in[17];
    const float* bf  = (const float*)d_in[18];
    float* out = (float*)d_out;

    char* wsb = (char*)d_ws;
    float* xcur = (float*)(wsb + 0);           // 3 MB fp32
    short* x2b  = (short*)(wsb + 3145728);     // 1.5 MB bf16
    short* qb   = (short*)(wsb + 4718592);     // 1.5 MB
    short* kb   = (short*)(wsb + 6291456);     // 0.75 MB
    short* vt   = (short*)(wsb + 7077888);     // 0.75 MB  [b][h][d][1536]
    short* attb = (short*)(wsb + 7864320);     // 1.5 MB
    short* hb   = (short*)(wsb + 9437184);     // 6 MB
    short* wbuf = (short*)(wsb + 15728640);    // 1.5 MB

    hipMemcpyAsync(xcur, x, (size_t)NROWS * DIM * sizeof(float),
                   hipMemcpyDeviceToDevice, stream);
    wconv_kernel<<<768, 256, 0, stream>>>(Wq, Wk, Wv, Wo, W1, W2, wbuf);

    for (int i = 0; i < LAYERS; ++i) {
        const short* wob = wbuf + 196608 + i * 16384;
        const short* w1b = wbuf + 262144 + i * 65536;
        const short* w2b = wbuf + 524288 + i * 65536;

        ln_kernel<<<NROWS / 4, 256, 0, stream>>>(xcur, x2b, g1 + i * DIM, bn1 + i * DIM);
        qkv_kernel<<<dim3(2, 48, 3), 256, 0, stream>>>(x2b, wbuf, bq, bk, bv, i, qb, kb, vt);
        attn_kernel<<<384, 256, 0, stream>>>(qb, kb, vt, attb);
        res_gemm<<<dim3(2, 48), 256, 0, stream>>>(attb, wob, bo + i * DIM, xcur, 128);
        ln_kernel<<<NROWS / 4, 256, 0, stream>>>(xcur, x2b, g2 + i * DIM, bn2 + i * DIM);
        gelu_gemm<<<dim3(8, 48), 256, 0, stream>>>(x2b, w1b, b1 + i * DFF, hb);
        res_gemm<<<dim3(2, 48), 256, 0, stream>>>(hb, w2b, b2 + i * DIM, xcur, 512);
    }
    final_kernel<<<NROWS / 4, 256, 0, stream>>>(xcur, Wf, bf, out);
}